// Round 1
// baseline (921.953 us; speedup 1.0000x reference)
//
#include <hip/hip_runtime.h>
#include <hip/hip_bf16.h>
#include <stdint.h>

// Problem constants
#define HW    65536          // 256*256
#define NB    4              // batch
#define CIN   192            // dim
#define OYC   288            // 192 q + 96 kv conv1x1 outputs
#define QP2   264            // padded LDS row stride (bf16) for conflict-free QK reads
#define BSTR  200            // B-tile LDS row stride (bf16): 100 words -> 4-bank lane shift

// ---- bf16 helpers (bf16 bits<<16 == fp32 bits) ----
__device__ __forceinline__ float bflo(unsigned u){ return __uint_as_float(u << 16); }
__device__ __forceinline__ float bfhi(unsigned u){ return __uint_as_float(u & 0xffff0000u); }
__device__ __forceinline__ float bf2f(__hip_bfloat16 v){ return __bfloat162float(v); }
__device__ __forceinline__ unsigned short f2bfbits(float f){
  __hip_bfloat16 h = __float2bfloat16(f); return *(unsigned short*)&h;
}

__device__ __forceinline__ void unpack8(uint4 u, float* f) {
  f[0]=bflo(u.x); f[1]=bfhi(u.x); f[2]=bflo(u.y); f[3]=bfhi(u.y);
  f[4]=bflo(u.z); f[5]=bfhi(u.z); f[6]=bflo(u.w); f[7]=bfhi(u.w);
}

union BF8 { uint4 u; __hip_bfloat16 h[8]; };

typedef __attribute__((ext_vector_type(8))) short short8;
typedef __attribute__((ext_vector_type(4))) float floatx4;

// ============================================================================
// K0: fold ln_w into W, emit A in MFMA-fragment order (bf16) + bias.
// AF[((ot*6+ks)*64 + lane)*8 + j] = W[ot*16 + (lane&15)][ks*32 + (lane>>4)*8 + j]
// ============================================================================
__global__ void k_prep(const float* __restrict__ qw, const float* __restrict__ kvw,
                       const float* __restrict__ lnw, const float* __restrict__ lnb,
                       __hip_bfloat16* __restrict__ AF, float* __restrict__ bias) {
  int t = threadIdx.x;
  for (int i = t; i < OYC * CIN; i += 256) {
    int o = i / CIN, c = i % CIN;
    float w = (o < 192) ? qw[o * 192 + c] : kvw[(o - 192) * 192 + c];
    float val = w * lnw[c];
    int ot = o >> 4, lo = o & 15;
    int ks = c >> 5, cr = c & 31, q = cr >> 3, j = cr & 7;
    int dst = (((ot * 6 + ks) * 64) + q * 16 + lo) * 8 + j;
    AF[dst] = __float2bfloat16(val);
  }
  for (int o = t; o < OYC; o += 256) {
    float s = 0.f;
    for (int c = 0; c < CIN; ++c)
      s += ((o < 192) ? qw[o * 192 + c] : kvw[(o - 192) * 192 + c]) * lnb[c];
    bias[o] = s;
  }
}

// ============================================================================
// K1: fused LayerNorm + conv1x1 via bf16 MFMA 16x16x32.
//     Block = 64 pixels x all 288 outputs (x read once). Waves: wo = o-half
//     (144 rows = 9 tiles), wn = px-half (32 = 2 subtiles). A frags streamed
//     from L2 (fragment-ordered global), B tile in LDS.
// ============================================================================
__global__ __launch_bounds__(256, 4) void k_conv1(const float* __restrict__ x,
                                                  const __hip_bfloat16* __restrict__ AF,
                                                  const float* __restrict__ bias,
                                                  __hip_bfloat16* __restrict__ y) {
  __shared__ __align__(16) __hip_bfloat16 Bl[64 * BSTR];
  __shared__ float part[4][64][2];
  __shared__ float murs[64][2];
  __shared__ float biasl[OYC];
  int bid = blockIdx.x;
  int b  = bid >> 10;
  int n0 = (bid & 1023) * 64;
  int tid = threadIdx.x;
  int p = tid & 63, g = tid >> 6;

  for (int i = tid; i < OYC; i += 256) biasl[i] = bias[i];

  // phase 1: load 48 channels of pixel p into regs (coalesced), LN stats
  const float* xb = x + (size_t)(b * CIN + g * 48) * HW + n0 + p;
  float xv[48];
  float s = 0.f, ss = 0.f;
#pragma unroll
  for (int j = 0; j < 48; ++j) {
    float v = xb[(size_t)j * HW];
    xv[j] = v; s += v; ss += v * v;
  }
  part[g][p][0] = s; part[g][p][1] = ss;
  __syncthreads();
  if (tid < 64) {
    float s0 = 0.f, s1 = 0.f;
#pragma unroll
    for (int gg = 0; gg < 4; ++gg) { s0 += part[gg][tid][0]; s1 += part[gg][tid][1]; }
    float m = s0 * (1.f / CIN);
    float var = s1 * (1.f / CIN) - m * m;
    murs[tid][0] = m; murs[tid][1] = rsqrtf(var + 1e-5f);
  }
  __syncthreads();
  float mu = murs[p][0], rs = murs[p][1];
#pragma unroll
  for (int j = 0; j < 48; j += 2) {
    unsigned lo = f2bfbits((xv[j]     - mu) * rs);
    unsigned hi = f2bfbits((xv[j + 1] - mu) * rs);
    *(unsigned*)&Bl[p * BSTR + g * 48 + j] = lo | (hi << 16);
  }
  __syncthreads();

  // phase 2: MFMA. wave wo owns o rows [wo*144, +144) = 9 tiles; wn owns px half.
  int wave = tid >> 6, lane = tid & 63;
  int wo = wave >> 1, wn = wave & 1;
  int li = lane & 15, q = lane >> 4;

  floatx4 acc[9][2];
#pragma unroll
  for (int t = 0; t < 9; ++t)
#pragma unroll
    for (int nt = 0; nt < 2; ++nt) acc[t][nt] = (floatx4){0.f, 0.f, 0.f, 0.f};

  for (int ks = 0; ks < 6; ++ks) {
    short8 bf[2];
#pragma unroll
    for (int nt = 0; nt < 2; ++nt) {
      int pp = wn * 32 + nt * 16 + li;
      bf[nt] = *(const short8*)&Bl[pp * BSTR + ks * 32 + q * 8];
    }
    const __hip_bfloat16* ap = AF + (((wo * 9) * 6 + ks) * 64 + lane) * 8;
#pragma unroll
    for (int t = 0; t < 9; ++t) {
      short8 af = *(const short8*)(ap + t * 6 * 64 * 8);
      acc[t][0] = __builtin_amdgcn_mfma_f32_16x16x32_bf16(af, bf[0], acc[t][0], 0, 0, 0);
      acc[t][1] = __builtin_amdgcn_mfma_f32_16x16x32_bf16(af, bf[1], acc[t][1], 0, 0, 0);
    }
  }

  // epilogue: D row = q*4+r, col = li
#pragma unroll
  for (int t = 0; t < 9; ++t) {
#pragma unroll
    for (int nt = 0; nt < 2; ++nt) {
#pragma unroll
      for (int r = 0; r < 4; ++r) {
        int o = (wo * 9 + t) * 16 + q * 4 + r;
        int pp = wn * 32 + nt * 16 + li;
        y[(size_t)(b * OYC + o) * HW + n0 + pp] = __float2bfloat16(acc[t][nt][r] + biasl[o]);
      }
    }
  }
}

// ============================================================================
// K2: depthwise 3x3 over kv channels. Block = (b, ch, 16-row tile).
// ============================================================================
__global__ __launch_bounds__(256) void k_dwkv(const __hip_bfloat16* __restrict__ y,
                                              const float* __restrict__ kvdw,
                                              __hip_bfloat16* __restrict__ kbuf,
                                              __hip_bfloat16* __restrict__ vbuf,
                                              float* __restrict__ kss) {
  __shared__ __align__(16) __hip_bfloat16 stage[18 * 256];
  int bid = blockIdx.x;
  int hb = bid & 15;                  // 16 row-tiles
  int ck = (bid >> 4) % 96;
  int b  = bid / (16 * 96);
  int tid = threadIdx.x;
  int h0 = hb * 16;

  const __hip_bfloat16* yp = y + (size_t)(b * OYC + 192 + ck) * HW;
  for (int i = tid; i < 18 * 32; i += 256) {
    int ry = i >> 5, seg = i & 31;
    int hh = h0 - 1 + ry;
    uint4 u = make_uint4(0u, 0u, 0u, 0u);
    if ((unsigned)hh < 256u) u = *(const uint4*)(yp + hh * 256 + seg * 8);
    *(uint4*)&stage[ry * 256 + seg * 8] = u;
  }
  __syncthreads();

  float w[9];
#pragma unroll
  for (int i = 0; i < 9; ++i) w[i] = kvdw[ck * 9 + i];

  int cg = tid & 31, rg = tid >> 5;   // 8 rowpairs x 32 colgroups
  int c0 = cg * 8;
  bool isk = (ck < 48);
  __hip_bfloat16* ob = (isk ? kbuf : vbuf) + (size_t)(b * 48 + (ck % 48)) * HW;
  float ssq = 0.f;
#pragma unroll
  for (int rr = 0; rr < 2; ++rr) {
    int orow = rg * 2 + rr;
    float o[8];
#pragma unroll
    for (int j = 0; j < 8; ++j) o[j] = 0.f;
#pragma unroll
    for (int ry = 0; ry < 3; ++ry) {
      const __hip_bfloat16* rb = &stage[(orow + ry) * 256];
      float v[8];
      unpack8(*(const uint4*)&rb[c0], v);
      float vl = (c0 > 0)       ? bf2f(rb[c0 - 1]) : 0.f;
      float vr = (c0 + 8 < 256) ? bf2f(rb[c0 + 8]) : 0.f;
      float wl = w[ry * 3], wm = w[ry * 3 + 1], wr = w[ry * 3 + 2];
      o[0] = fmaf(wl, vl, fmaf(wm, v[0], fmaf(wr, v[1], o[0])));
#pragma unroll
      for (int j = 1; j < 7; ++j)
        o[j] = fmaf(wl, v[j-1], fmaf(wm, v[j], fmaf(wr, v[j+1], o[j])));
      o[7] = fmaf(wl, v[6], fmaf(wm, v[7], fmaf(wr, vr, o[7])));
    }
    BF8 t;
#pragma unroll
    for (int j = 0; j < 8; ++j) {
      t.h[j] = __float2bfloat16(o[j]);
      if (isk) { float fv = bf2f(t.h[j]); ssq += fv * fv; }
    }
    *(uint4*)(ob + (size_t)(h0 + orow) * 256 + c0) = t.u;
  }
  if (isk) {
#pragma unroll
    for (int off = 32; off > 0; off >>= 1) ssq += __shfl_down(ssq, off);
    __shared__ float ws4[4];
    if ((tid & 63) == 0) ws4[tid >> 6] = ssq;
    __syncthreads();
    if (tid == 0) atomicAdd(&kss[b * 48 + ck], ws4[0] + ws4[1] + ws4[2] + ws4[3]);
  }
}

// ============================================================================
// K3: per (b, kvh, qhalf, row): staged dwconv of 48 q channels -> ql (LDS),
//     fused sum(q^2) and partial QK^T, in-block reduce, atomicAdd logits.
// ============================================================================
__global__ __launch_bounds__(256) void k_dwq_attn(const __hip_bfloat16* __restrict__ y,
                                                  const float* __restrict__ qdw,
                                                  const __hip_bfloat16* __restrict__ kbuf,
                                                  float* __restrict__ qss,
                                                  float* __restrict__ attn) {
  __shared__ __align__(16) __hip_bfloat16 kl[24 * 256];
  __shared__ __align__(16) __hip_bfloat16 ql[48 * QP2];
  __shared__ __align__(16) __hip_bfloat16 stage[12 * 3 * 256];
  __shared__ float red[128 * 9];

  int bid = blockIdx.x;
  int h   = bid & 255;
  int qh  = (bid >> 8) & 1;
  int kvh = (bid >> 9) & 1;
  int b   = bid >> 10;
  int tid = threadIdx.x;

  // load k tile (24 rows x 256 cols)
  const __hip_bfloat16* kp = kbuf + (size_t)(b * 48 + kvh * 24) * HW + h * 256;
  for (int i = tid; i < 24 * 32; i += 256) {
    int d = i >> 5, seg = i & 31;
    *(uint4*)&kl[d * 256 + seg * 8] = *(const uint4*)(kp + (size_t)d * HW + seg * 8);
  }

  // dwconv 48 channels in 4 chunks of 12
  for (int chunk = 0; chunk < 4; ++chunk) {
    __syncthreads();   // protect stage from previous chunk's readers
    for (int i = tid; i < 12 * 3 * 32; i += 256) {
      int seg = i & 31, rr = i >> 5;
      int ch = rr / 3, ry = rr % 3;
      int cg = kvh * 96 + qh * 48 + chunk * 12 + ch;
      int hh = h + ry - 1;
      uint4 u = make_uint4(0u, 0u, 0u, 0u);
      if ((unsigned)hh < 256u)
        u = *(const uint4*)(y + (size_t)(b * OYC + cg) * HW + hh * 256 + seg * 8);
      *(uint4*)&stage[(ch * 3 + ry) * 256 + seg * 8] = u;
    }
    __syncthreads();
    for (int i = tid; i < 384; i += 256) {
      int ch = i >> 5, cg = i & 31;
      int c0 = cg * 8;
      int cgl = kvh * 96 + qh * 48 + chunk * 12 + ch;
      const float* wp = qdw + cgl * 9;
      float o[8];
#pragma unroll
      for (int j = 0; j < 8; ++j) o[j] = 0.f;
#pragma unroll
      for (int ry = 0; ry < 3; ++ry) {
        const __hip_bfloat16* rb = &stage[(ch * 3 + ry) * 256];
        float v[8];
        unpack8(*(const uint4*)&rb[c0], v);
        float vl = (c0 > 0)       ? bf2f(rb[c0 - 1]) : 0.f;
        float vr = (c0 + 8 < 256) ? bf2f(rb[c0 + 8]) : 0.f;
        float wl = wp[ry * 3], wm = wp[ry * 3 + 1], wr = wp[ry * 3 + 2];
        o[0] = fmaf(wl, vl, fmaf(wm, v[0], fmaf(wr, v[1], o[0])));
#pragma unroll
        for (int j = 1; j < 7; ++j)
          o[j] = fmaf(wl, v[j-1], fmaf(wm, v[j], fmaf(wr, v[j+1], o[j])));
        o[7] = fmaf(wl, v[6], fmaf(wm, v[7], fmaf(wr, vr, o[7])));
      }
      BF8 t;
#pragma unroll
      for (int j = 0; j < 8; ++j) t.h[j] = __float2bfloat16(o[j]);
      *(uint4*)&ql[(chunk * 12 + ch) * QP2 + c0] = t.u;
    }
  }
  __syncthreads();   // ql + kl complete

  // sum(q^2) per channel
  if (tid < 48) {
    float s = 0.f;
    for (int n = 0; n < 256; n += 8) {
      float f[8];
      unpack8(*(const uint4*)&ql[tid * QP2 + n], f);
#pragma unroll
      for (int e = 0; e < 8; ++e) s += f[e] * f[e];
    }
    atomicAdd(&qss[b * 192 + kvh * 96 + qh * 48 + tid], s);
  }

  // QK^T partials: thread = (nhalf, ccg(16) x dg(8)) -> 3x3 tile over 128 n
  int nhalf = tid >> 7, r = tid & 127;
  int ccg = r >> 3, dg = r & 7;
  int cc0 = ccg * 3, d0 = dg * 3;
  float acc[9];
#pragma unroll
  for (int i = 0; i < 9; ++i) acc[i] = 0.f;
  for (int n = nhalf * 128; n < nhalf * 128 + 128; n += 8) {
    float a[3][8], bv[3][8];
#pragma unroll
    for (int i = 0; i < 3; ++i) unpack8(*(const uint4*)&ql[(cc0 + i) * QP2 + n], a[i]);
#pragma unroll
    for (int j = 0; j < 3; ++j) unpack8(*(const uint4*)&kl[(d0 + j) * 256 + n], bv[j]);
#pragma unroll
    for (int i = 0; i < 3; ++i)
#pragma unroll
      for (int j = 0; j < 3; ++j)
#pragma unroll
        for (int e = 0; e < 8; ++e)
          acc[i * 3 + j] = fmaf(a[i][e], bv[j][e], acc[i * 3 + j]);
  }
  if (nhalf == 1) {
#pragma unroll
    for (int i = 0; i < 9; ++i) red[r * 9 + i] = acc[i];
  }
  __syncthreads();
  if (nhalf == 0) {
#pragma unroll
    for (int i = 0; i < 9; ++i) acc[i] += red[r * 9 + i];
#pragma unroll
    for (int i = 0; i < 3; ++i)
#pragma unroll
      for (int j = 0; j < 3; ++j) {
        int cc = qh * 48 + cc0 + i, d = d0 + j;
        int head = kvh * 4 + cc / 24, cp = cc % 24;
        atomicAdd(&attn[(((b * 8 + head) * 24) + cp) * 24 + d], acc[i * 3 + j]);
      }
  }
}

// ============================================================================
// K4: l2norm scaling + temperature + softmax, then fold proj_w through attn:
//     Mt[b][j=kvh*24+d][o] = sum_cc proj[o][kvh*96+cc] * attnS[kvh*96+cc][d]
// ============================================================================
__global__ void k_attn_final(const float* __restrict__ attn, const float* __restrict__ qss,
                             const float* __restrict__ kss, const float* __restrict__ temp,
                             const float* __restrict__ projw, float* __restrict__ Mt) {
  int b = blockIdx.x;
  int t = threadIdx.x;
  __shared__ float as_[96 * 25];
  float acc[48];
#pragma unroll
  for (int j = 0; j < 48; ++j) acc[j] = 0.f;
  for (int kvh = 0; kvh < 2; ++kvh) {
    __syncthreads();
    if (t < 96) {
      int row = kvh * 96 + t;           // global q channel
      int h = row / 24, cp = row % 24;
      float rq = 1.f / fmaxf(sqrtf(qss[b * 192 + row]), 1e-12f);
      float tp = temp[h];
      float lg[24]; float mx = -1e30f;
#pragma unroll
      for (int d = 0; d < 24; ++d) {
        float rk = 1.f / fmaxf(sqrtf(kss[b * 48 + kvh * 24 + d]), 1e-12f);
        float l = attn[(((b * 8 + h) * 24) + cp) * 24 + d] * rq * rk * tp;
        lg[d] = l; mx = fmaxf(mx, l);
      }
      float s = 0.f;
#pragma unroll
      for (int d = 0; d < 24; ++d) { lg[d] = __expf(lg[d] - mx); s += lg[d]; }
      float inv = 1.f / s;
#pragma unroll
      for (int d = 0; d < 24; ++d) as_[t * 25 + d] = lg[d] * inv;
    }
    __syncthreads();
    if (t < 192) {
      for (int cc = 0; cc < 96; ++cc) {
        float pw = projw[t * 192 + kvh * 96 + cc];
        const float* ar = &as_[cc * 25];
#pragma unroll
        for (int d = 0; d < 24; ++d) acc[kvh * 24 + d] = fmaf(pw, ar[d], acc[kvh * 24 + d]);
      }
    }
  }
  if (t < 192) {
#pragma unroll
    for (int j = 0; j < 48; ++j) Mt[((size_t)b * 48 + j) * 192 + t] = acc[j];
  }
}

// ============================================================================
// K5: out[b][o][n] = sum_j Mt[b][j][o] * v[b][j][n]   (fp32 output)
// ============================================================================
__global__ __launch_bounds__(256) void k_out(const __hip_bfloat16* __restrict__ vbuf,
                                             const float* __restrict__ Mt,
                                             float* __restrict__ out) {
  __shared__ float lv[48 * 64];
  int bid = blockIdx.x;
  int b  = bid >> 10;
  int n0 = (bid & 1023) * 64;
  int tid = threadIdx.x;
  const __hip_bfloat16* vb = vbuf + (size_t)b * 48 * HW + n0;
  for (int i = tid; i < 48 * 64; i += 256) {
    int c = i >> 6, tn = i & 63;
    lv[i] = bf2f(vb[(size_t)c * HW + tn]);
  }
  __syncthreads();
  int wave = __builtin_amdgcn_readfirstlane(tid >> 6);
  int tn = tid & 63;
  const float* mb = Mt + (size_t)b * 48 * 192;
  for (int ch = 0; ch < 2; ++ch) {
    int o0 = wave * 48 + ch * 24;
    float acc[24];
#pragma unroll
    for (int j = 0; j < 24; ++j) acc[j] = 0.f;
    for (int c = 0; c < 48; ++c) {
      float xv = lv[c * 64 + tn];
#pragma unroll
      for (int j = 0; j < 24; ++j) acc[j] = fmaf(mb[c * 192 + o0 + j], xv, acc[j]);
    }
    float* op = out + ((size_t)b * 192 + o0) * HW + n0 + tn;
#pragma unroll
    for (int j = 0; j < 24; ++j) op[(size_t)j * HW] = acc[j];
  }
}

// ============================================================================
// ws layout (float offsets):
//  0        qss   [4*192]      = 768
//  768      kss   [4*48]       = 192
//  960      attn  [4*8*24*24]  = 18432
//  19392    Mt    [4*48*192]   = 36864
//  56256    bias  [288]
//  56544    AF  bf16 [288*192] (= 27648 float slots)
//  111872   y   bf16 [4*288*HW]
//  37860608 kbuf bf16 [4*48*HW]
//  44152064 vbuf bf16 [4*48*HW]
// ============================================================================
extern "C" void kernel_launch(void* const* d_in, const int* in_sizes, int n_in,
                              void* d_out, int out_size, void* d_ws, size_t ws_size,
                              hipStream_t stream) {
  const float* x     = (const float*)d_in[0];
  const float* ln_w  = (const float*)d_in[1];
  const float* ln_b  = (const float*)d_in[2];
  const float* q_w   = (const float*)d_in[3];
  const float* q_dw  = (const float*)d_in[4];
  const float* kv_w  = (const float*)d_in[5];
  const float* kv_dw = (const float*)d_in[6];
  const float* projw = (const float*)d_in[7];
  const float* temp  = (const float*)d_in[8];
  float* out = (float*)d_out;
  float* wsf = (float*)d_ws;

  float* qss  = wsf;
  float* kss  = wsf + 768;
  float* attn = wsf + 960;
  float* Mt   = wsf + 19392;
  float* bias = wsf + 56256;
  __hip_bfloat16* AF = (__hip_bfloat16*)(wsf + 56544);
  __hip_bfloat16* y    = (__hip_bfloat16*)(wsf + 111872);
  __hip_bfloat16* kbuf = (__hip_bfloat16*)(wsf + 37860608);
  __hip_bfloat16* vbuf = (__hip_bfloat16*)(wsf + 44152064);

  hipMemsetAsync(wsf, 0, 19392 * sizeof(float), stream);  // qss+kss+attn accumulators
  hipLaunchKernelGGL(k_prep, dim3(1), dim3(256), 0, stream, q_w, kv_w, ln_w, ln_b, AF, bias);
  hipLaunchKernelGGL(k_conv1, dim3(NB * 1024), dim3(256), 0, stream, x, AF, bias, y);
  hipLaunchKernelGGL(k_dwkv, dim3(NB * 96 * 16), dim3(256), 0, stream, y, kv_dw, kbuf, vbuf, kss);
  hipLaunchKernelGGL(k_dwq_attn, dim3(NB * 2 * 2 * 256), dim3(256), 0, stream, y, q_dw, kbuf, qss, attn);
  hipLaunchKernelGGL(k_attn_final, dim3(NB), dim3(256), 0, stream, attn, qss, kss, temp, projw, Mt);
  hipLaunchKernelGGL(k_out, dim3(NB * 1024), dim3(256), 0, stream, vbuf, Mt, out);
}

// Round 2
// 679.869 us; speedup vs baseline: 1.3561x; 1.3561x over previous
//
#include <hip/hip_runtime.h>
#include <hip/hip_bf16.h>
#include <stdint.h>

// Problem constants
#define HW    65536          // 256*256
#define NB    4              // batch
#define CIN   192            // dim
#define OYC   288            // 192 q + 96 kv conv1x1 outputs
#define BSTR  200            // B-tile LDS row stride (bf16): 100 words -> 4-bank lane shift

// ---- bf16 helpers (bf16 bits<<16 == fp32 bits) ----
__device__ __forceinline__ float bflo(unsigned u){ return __uint_as_float(u << 16); }
__device__ __forceinline__ float bfhi(unsigned u){ return __uint_as_float(u & 0xffff0000u); }
__device__ __forceinline__ float bf2f(__hip_bfloat16 v){ return __bfloat162float(v); }
__device__ __forceinline__ unsigned short f2bfbits(float f){
  __hip_bfloat16 h = __float2bfloat16(f); return *(unsigned short*)&h;
}

__device__ __forceinline__ void unpack8(uint4 u, float* f) {
  f[0]=bflo(u.x); f[1]=bfhi(u.x); f[2]=bflo(u.y); f[3]=bfhi(u.y);
  f[4]=bflo(u.z); f[5]=bfhi(u.z); f[6]=bflo(u.w); f[7]=bfhi(u.w);
}

union BF8 { uint4 u; __hip_bfloat16 h[8]; };

typedef __attribute__((ext_vector_type(8))) short short8;
typedef __attribute__((ext_vector_type(4))) float floatx4;

// ============================================================================
// K0: fold ln_w into W, emit A in MFMA-fragment order (bf16) + bias.
// AF[((ot*6+ks)*64 + lane)*8 + j] = W[ot*16 + (lane&15)][ks*32 + (lane>>4)*8 + j]
// ============================================================================
__global__ void k_prep(const float* __restrict__ qw, const float* __restrict__ kvw,
                       const float* __restrict__ lnw, const float* __restrict__ lnb,
                       __hip_bfloat16* __restrict__ AF, float* __restrict__ bias) {
  int t = threadIdx.x;
  for (int i = t; i < OYC * CIN; i += 256) {
    int o = i / CIN, c = i % CIN;
    float w = (o < 192) ? qw[o * 192 + c] : kvw[(o - 192) * 192 + c];
    float val = w * lnw[c];
    int ot = o >> 4, lo = o & 15;
    int ks = c >> 5, cr = c & 31, q = cr >> 3, j = cr & 7;
    int dst = (((ot * 6 + ks) * 64) + q * 16 + lo) * 8 + j;
    AF[dst] = __float2bfloat16(val);
  }
  for (int o = t; o < OYC; o += 256) {
    float s = 0.f;
    for (int c = 0; c < CIN; ++c)
      s += ((o < 192) ? qw[o * 192 + c] : kvw[(o - 192) * 192 + c]) * lnb[c];
    bias[o] = s;
  }
}

// ============================================================================
// K1: fused LayerNorm + conv1x1 via bf16 MFMA 16x16x32. (unchanged)
// ============================================================================
__global__ __launch_bounds__(256, 4) void k_conv1(const float* __restrict__ x,
                                                  const __hip_bfloat16* __restrict__ AF,
                                                  const float* __restrict__ bias,
                                                  __hip_bfloat16* __restrict__ y) {
  __shared__ __align__(16) __hip_bfloat16 Bl[64 * BSTR];
  __shared__ float part[4][64][2];
  __shared__ float murs[64][2];
  __shared__ float biasl[OYC];
  int bid = blockIdx.x;
  int b  = bid >> 10;
  int n0 = (bid & 1023) * 64;
  int tid = threadIdx.x;
  int p = tid & 63, g = tid >> 6;

  for (int i = tid; i < OYC; i += 256) biasl[i] = bias[i];

  const float* xb = x + (size_t)(b * CIN + g * 48) * HW + n0 + p;
  float xv[48];
  float s = 0.f, ss = 0.f;
#pragma unroll
  for (int j = 0; j < 48; ++j) {
    float v = xb[(size_t)j * HW];
    xv[j] = v; s += v; ss += v * v;
  }
  part[g][p][0] = s; part[g][p][1] = ss;
  __syncthreads();
  if (tid < 64) {
    float s0 = 0.f, s1 = 0.f;
#pragma unroll
    for (int gg = 0; gg < 4; ++gg) { s0 += part[gg][tid][0]; s1 += part[gg][tid][1]; }
    float m = s0 * (1.f / CIN);
    float var = s1 * (1.f / CIN) - m * m;
    murs[tid][0] = m; murs[tid][1] = rsqrtf(var + 1e-5f);
  }
  __syncthreads();
  float mu = murs[p][0], rs = murs[p][1];
#pragma unroll
  for (int j = 0; j < 48; j += 2) {
    unsigned lo = f2bfbits((xv[j]     - mu) * rs);
    unsigned hi = f2bfbits((xv[j + 1] - mu) * rs);
    *(unsigned*)&Bl[p * BSTR + g * 48 + j] = lo | (hi << 16);
  }
  __syncthreads();

  int wave = tid >> 6, lane = tid & 63;
  int wo = wave >> 1, wn = wave & 1;
  int li = lane & 15, q = lane >> 4;

  floatx4 acc[9][2];
#pragma unroll
  for (int t = 0; t < 9; ++t)
#pragma unroll
    for (int nt = 0; nt < 2; ++nt) acc[t][nt] = (floatx4){0.f, 0.f, 0.f, 0.f};

  for (int ks = 0; ks < 6; ++ks) {
    short8 bf[2];
#pragma unroll
    for (int nt = 0; nt < 2; ++nt) {
      int pp = wn * 32 + nt * 16 + li;
      bf[nt] = *(const short8*)&Bl[pp * BSTR + ks * 32 + q * 8];
    }
    const __hip_bfloat16* ap = AF + (((wo * 9) * 6 + ks) * 64 + lane) * 8;
#pragma unroll
    for (int t = 0; t < 9; ++t) {
      short8 af = *(const short8*)(ap + t * 6 * 64 * 8);
      acc[t][0] = __builtin_amdgcn_mfma_f32_16x16x32_bf16(af, bf[0], acc[t][0], 0, 0, 0);
      acc[t][1] = __builtin_amdgcn_mfma_f32_16x16x32_bf16(af, bf[1], acc[t][1], 0, 0, 0);
    }
  }

#pragma unroll
  for (int t = 0; t < 9; ++t) {
#pragma unroll
    for (int nt = 0; nt < 2; ++nt) {
#pragma unroll
      for (int r = 0; r < 4; ++r) {
        int o = (wo * 9 + t) * 16 + q * 4 + r;
        int pp = wn * 32 + nt * 16 + li;
        y[(size_t)(b * OYC + o) * HW + n0 + pp] = __float2bfloat16(acc[t][nt][r] + biasl[o]);
      }
    }
  }
}

// ============================================================================
// K2: depthwise 3x3 over kv channels. Block = (b, ch, 16-row tile). (unchanged)
// ============================================================================
__global__ __launch_bounds__(256) void k_dwkv(const __hip_bfloat16* __restrict__ y,
                                              const float* __restrict__ kvdw,
                                              __hip_bfloat16* __restrict__ kbuf,
                                              __hip_bfloat16* __restrict__ vbuf,
                                              float* __restrict__ kss) {
  __shared__ __align__(16) __hip_bfloat16 stage[18 * 256];
  int bid = blockIdx.x;
  int hb = bid & 15;                  // 16 row-tiles
  int ck = (bid >> 4) % 96;
  int b  = bid / (16 * 96);
  int tid = threadIdx.x;
  int h0 = hb * 16;

  const __hip_bfloat16* yp = y + (size_t)(b * OYC + 192 + ck) * HW;
  for (int i = tid; i < 18 * 32; i += 256) {
    int ry = i >> 5, seg = i & 31;
    int hh = h0 - 1 + ry;
    uint4 u = make_uint4(0u, 0u, 0u, 0u);
    if ((unsigned)hh < 256u) u = *(const uint4*)(yp + hh * 256 + seg * 8);
    *(uint4*)&stage[ry * 256 + seg * 8] = u;
  }
  __syncthreads();

  float w[9];
#pragma unroll
  for (int i = 0; i < 9; ++i) w[i] = kvdw[ck * 9 + i];

  int cg = tid & 31, rg = tid >> 5;   // 8 rowpairs x 32 colgroups
  int c0 = cg * 8;
  bool isk = (ck < 48);
  __hip_bfloat16* ob = (isk ? kbuf : vbuf) + (size_t)(b * 48 + (ck % 48)) * HW;
  float ssq = 0.f;
#pragma unroll
  for (int rr = 0; rr < 2; ++rr) {
    int orow = rg * 2 + rr;
    float o[8];
#pragma unroll
    for (int j = 0; j < 8; ++j) o[j] = 0.f;
#pragma unroll
    for (int ry = 0; ry < 3; ++ry) {
      const __hip_bfloat16* rb = &stage[(orow + ry) * 256];
      float v[8];
      unpack8(*(const uint4*)&rb[c0], v);
      float vl = (c0 > 0)       ? bf2f(rb[c0 - 1]) : 0.f;
      float vr = (c0 + 8 < 256) ? bf2f(rb[c0 + 8]) : 0.f;
      float wl = w[ry * 3], wm = w[ry * 3 + 1], wr = w[ry * 3 + 2];
      o[0] = fmaf(wl, vl, fmaf(wm, v[0], fmaf(wr, v[1], o[0])));
#pragma unroll
      for (int j = 1; j < 7; ++j)
        o[j] = fmaf(wl, v[j-1], fmaf(wm, v[j], fmaf(wr, v[j+1], o[j])));
      o[7] = fmaf(wl, v[6], fmaf(wm, v[7], fmaf(wr, vr, o[7])));
    }
    BF8 t;
#pragma unroll
    for (int j = 0; j < 8; ++j) {
      t.h[j] = __float2bfloat16(o[j]);
      if (isk) { float fv = bf2f(t.h[j]); ssq += fv * fv; }
    }
    *(uint4*)(ob + (size_t)(h0 + orow) * 256 + c0) = t.u;
  }
  if (isk) {
#pragma unroll
    for (int off = 32; off > 0; off >>= 1) ssq += __shfl_down(ssq, off);
    __shared__ float ws4[4];
    if ((tid & 63) == 0) ws4[tid >> 6] = ssq;
    __syncthreads();
    if (tid == 0) atomicAdd(&kss[b * 48 + ck], ws4[0] + ws4[1] + ws4[2] + ws4[3]);
  }
}

// ============================================================================
// K3a: depthwise 3x3 over the 192 q channels -> qfull (scratch in d_out),
//      fused sum(q^2). Same 16-row-tile structure as k_dwkv (1.125x halo).
// ============================================================================
__global__ __launch_bounds__(256) void k_dwq(const __hip_bfloat16* __restrict__ y,
                                             const float* __restrict__ qdw,
                                             __hip_bfloat16* __restrict__ qfull,
                                             float* __restrict__ qss) {
  __shared__ __align__(16) __hip_bfloat16 stage[18 * 256];
  int bid = blockIdx.x;
  int hb = bid & 15;                  // 16 row-tiles
  int c  = (bid >> 4) % 192;
  int b  = bid / (16 * 192);
  int tid = threadIdx.x;
  int h0 = hb * 16;

  const __hip_bfloat16* yp = y + (size_t)(b * OYC + c) * HW;
  for (int i = tid; i < 18 * 32; i += 256) {
    int ry = i >> 5, seg = i & 31;
    int hh = h0 - 1 + ry;
    uint4 u = make_uint4(0u, 0u, 0u, 0u);
    if ((unsigned)hh < 256u) u = *(const uint4*)(yp + hh * 256 + seg * 8);
    *(uint4*)&stage[ry * 256 + seg * 8] = u;
  }
  __syncthreads();

  float w[9];
#pragma unroll
  for (int i = 0; i < 9; ++i) w[i] = qdw[c * 9 + i];

  int cg = tid & 31, rg = tid >> 5;   // 8 rowpairs x 32 colgroups
  int c0 = cg * 8;
  __hip_bfloat16* ob = qfull + (size_t)(b * CIN + c) * HW;
  float ssq = 0.f;
#pragma unroll
  for (int rr = 0; rr < 2; ++rr) {
    int orow = rg * 2 + rr;
    float o[8];
#pragma unroll
    for (int j = 0; j < 8; ++j) o[j] = 0.f;
#pragma unroll
    for (int ry = 0; ry < 3; ++ry) {
      const __hip_bfloat16* rb = &stage[(orow + ry) * 256];
      float v[8];
      unpack8(*(const uint4*)&rb[c0], v);
      float vl = (c0 > 0)       ? bf2f(rb[c0 - 1]) : 0.f;
      float vr = (c0 + 8 < 256) ? bf2f(rb[c0 + 8]) : 0.f;
      float wl = w[ry * 3], wm = w[ry * 3 + 1], wr = w[ry * 3 + 2];
      o[0] = fmaf(wl, vl, fmaf(wm, v[0], fmaf(wr, v[1], o[0])));
#pragma unroll
      for (int j = 1; j < 7; ++j)
        o[j] = fmaf(wl, v[j-1], fmaf(wm, v[j], fmaf(wr, v[j+1], o[j])));
      o[7] = fmaf(wl, v[6], fmaf(wm, v[7], fmaf(wr, vr, o[7])));
    }
    BF8 t;
#pragma unroll
    for (int j = 0; j < 8; ++j) {
      t.h[j] = __float2bfloat16(o[j]);
      float fv = bf2f(t.h[j]); ssq += fv * fv;
    }
    *(uint4*)(ob + (size_t)(h0 + orow) * 256 + c0) = t.u;
  }
#pragma unroll
  for (int off = 32; off > 0; off >>= 1) ssq += __shfl_down(ssq, off);
  __shared__ float ws4[4];
  if ((tid & 63) == 0) ws4[tid >> 6] = ssq;
  __syncthreads();
  if (tid == 0) atomicAdd(&qss[b * 192 + c], ws4[0] + ws4[1] + ws4[2] + ws4[3]);
}

// ============================================================================
// K3b: QK^T via bf16 MFMA. Per (b,kvh): GEMM M=96 (q ch), N=24 (k ch, 2 tiles
//      of 16 w/ clamp), K=65536 split into 64 chunks x 4 waves x 256 px.
//      Fragments loaded directly from global (rows L1/L2-resident).
//      Block reduce in LDS (atomic), one global atomicAdd per cell per block.
// ============================================================================
__global__ __launch_bounds__(256) void k_qk(const __hip_bfloat16* __restrict__ qfull,
                                            const __hip_bfloat16* __restrict__ kbuf,
                                            float* __restrict__ attn) {
  __shared__ float red[96 * 33];
  int bid = blockIdx.x;
  int ck  = bid & 63;
  int kvh = (bid >> 6) & 1;
  int b   = bid >> 7;
  int tid = threadIdx.x;
  int wave = tid >> 6, lane = tid & 63;
  int li = lane & 15, qd = lane >> 4;

  for (int i = tid; i < 96 * 33; i += 256) red[i] = 0.f;

  const __hip_bfloat16* qp = qfull + (size_t)(b * CIN + kvh * 96) * HW;
  const __hip_bfloat16* kp = kbuf  + (size_t)(b * 48 + kvh * 24) * HW;
  int n0 = ck * 1024 + wave * 256;

  floatx4 acc[6][2];
#pragma unroll
  for (int mt = 0; mt < 6; ++mt) {
    acc[mt][0] = (floatx4){0.f, 0.f, 0.f, 0.f};
    acc[mt][1] = (floatx4){0.f, 0.f, 0.f, 0.f};
  }

  int kr1 = 16 + li; if (kr1 > 23) kr1 = 23;   // clamp pad rows of N-tile 1
  for (int ks = 0; ks < 8; ++ks) {
    int nn = n0 + ks * 32 + qd * 8;
    short8 bk0 = *(const short8*)(kp + (size_t)li  * HW + nn);
    short8 bk1 = *(const short8*)(kp + (size_t)kr1 * HW + nn);
#pragma unroll
    for (int mt = 0; mt < 6; ++mt) {
      short8 aq = *(const short8*)(qp + (size_t)(mt * 16 + li) * HW + nn);
      acc[mt][0] = __builtin_amdgcn_mfma_f32_16x16x32_bf16(aq, bk0, acc[mt][0], 0, 0, 0);
      acc[mt][1] = __builtin_amdgcn_mfma_f32_16x16x32_bf16(aq, bk1, acc[mt][1], 0, 0, 0);
    }
  }
  __syncthreads();   // red[] zero complete

  // D layout: col = lane&15 (n = k-ch), row = (lane>>4)*4 + r (m within tile)
#pragma unroll
  for (int mt = 0; mt < 6; ++mt) {
#pragma unroll
    for (int nt = 0; nt < 2; ++nt) {
      int n = nt * 16 + li;
      if (n < 24) {
#pragma unroll
        for (int r = 0; r < 4; ++r) {
          int m = mt * 16 + qd * 4 + r;
          atomicAdd(&red[m * 33 + n], acc[mt][nt][r]);
        }
      }
    }
  }
  __syncthreads();

  for (int i = tid; i < 96 * 24; i += 256) {
    int m = i / 24, d = i % 24;
    int head = kvh * 4 + m / 24, cp = m % 24;
    atomicAdd(&attn[(((b * 8 + head) * 24) + cp) * 24 + d], red[m * 33 + d]);
  }
}

// ============================================================================
// K4: l2norm scaling + temperature + softmax, fold proj_w. (unchanged)
// ============================================================================
__global__ void k_attn_final(const float* __restrict__ attn, const float* __restrict__ qss,
                             const float* __restrict__ kss, const float* __restrict__ temp,
                             const float* __restrict__ projw, float* __restrict__ Mt) {
  int b = blockIdx.x;
  int t = threadIdx.x;
  __shared__ float as_[96 * 25];
  float acc[48];
#pragma unroll
  for (int j = 0; j < 48; ++j) acc[j] = 0.f;
  for (int kvh = 0; kvh < 2; ++kvh) {
    __syncthreads();
    if (t < 96) {
      int row = kvh * 96 + t;           // global q channel
      int h = row / 24, cp = row % 24;
      float rq = 1.f / fmaxf(sqrtf(qss[b * 192 + row]), 1e-12f);
      float tp = temp[h];
      float lg[24]; float mx = -1e30f;
#pragma unroll
      for (int d = 0; d < 24; ++d) {
        float rk = 1.f / fmaxf(sqrtf(kss[b * 48 + kvh * 24 + d]), 1e-12f);
        float l = attn[(((b * 8 + h) * 24) + cp) * 24 + d] * rq * rk * tp;
        lg[d] = l; mx = fmaxf(mx, l);
      }
      float s = 0.f;
#pragma unroll
      for (int d = 0; d < 24; ++d) { lg[d] = __expf(lg[d] - mx); s += lg[d]; }
      float inv = 1.f / s;
#pragma unroll
      for (int d = 0; d < 24; ++d) as_[t * 25 + d] = lg[d] * inv;
    }
    __syncthreads();
    if (t < 192) {
      for (int cc = 0; cc < 96; ++cc) {
        float pw = projw[t * 192 + kvh * 96 + cc];
        const float* ar = &as_[cc * 25];
#pragma unroll
        for (int d = 0; d < 24; ++d) acc[kvh * 24 + d] = fmaf(pw, ar[d], acc[kvh * 24 + d]);
      }
    }
  }
  if (t < 192) {
#pragma unroll
    for (int j = 0; j < 48; ++j) Mt[((size_t)b * 48 + j) * 192 + t] = acc[j];
  }
}

// ============================================================================
// K5: out[b][o][n] = sum_j Mt[b][j][o] * v[b][j][n]   (fp32 output, unchanged)
// ============================================================================
__global__ __launch_bounds__(256) void k_out(const __hip_bfloat16* __restrict__ vbuf,
                                             const float* __restrict__ Mt,
                                             float* __restrict__ out) {
  __shared__ float lv[48 * 64];
  int bid = blockIdx.x;
  int b  = bid >> 10;
  int n0 = (bid & 1023) * 64;
  int tid = threadIdx.x;
  const __hip_bfloat16* vb = vbuf + (size_t)b * 48 * HW + n0;
  for (int i = tid; i < 48 * 64; i += 256) {
    int c = i >> 6, tn = i & 63;
    lv[i] = bf2f(vb[(size_t)c * HW + tn]);
  }
  __syncthreads();
  int wave = __builtin_amdgcn_readfirstlane(tid >> 6);
  int tn = tid & 63;
  const float* mb = Mt + (size_t)b * 48 * 192;
  for (int ch = 0; ch < 2; ++ch) {
    int o0 = wave * 48 + ch * 24;
    float acc[24];
#pragma unroll
    for (int j = 0; j < 24; ++j) acc[j] = 0.f;
    for (int c = 0; c < 48; ++c) {
      float xv = lv[c * 64 + tn];
#pragma unroll
      for (int j = 0; j < 24; ++j) acc[j] = fmaf(mb[c * 192 + o0 + j], xv, acc[j]);
    }
    float* op = out + ((size_t)b * 192 + o0) * HW + n0 + tn;
#pragma unroll
    for (int j = 0; j < 24; ++j) op[(size_t)j * HW] = acc[j];
  }
}

// ============================================================================
// ws layout (float offsets):
//  0        qss   [4*192]      = 768
//  768      kss   [4*48]       = 192
//  960      attn  [4*8*24*24]  = 18432
//  19392    Mt    [4*48*192]   = 36864
//  56256    bias  [288]
//  56544    AF  bf16 [288*192] (= 27648 float slots)
//  111872   y   bf16 [4*288*HW]
//  37860608 kbuf bf16 [4*48*HW]
//  44152064 vbuf bf16 [4*48*HW]
// qfull (bf16 [4*192*HW] = 100.7 MB) lives in d_out scratch (201 MB fp32),
// dead before k_out overwrites it.
// ============================================================================
extern "C" void kernel_launch(void* const* d_in, const int* in_sizes, int n_in,
                              void* d_out, int out_size, void* d_ws, size_t ws_size,
                              hipStream_t stream) {
  const float* x     = (const float*)d_in[0];
  const float* ln_w  = (const float*)d_in[1];
  const float* ln_b  = (const float*)d_in[2];
  const float* q_w   = (const float*)d_in[3];
  const float* q_dw  = (const float*)d_in[4];
  const float* kv_w  = (const float*)d_in[5];
  const float* kv_dw = (const float*)d_in[6];
  const float* projw = (const float*)d_in[7];
  const float* temp  = (const float*)d_in[8];
  float* out = (float*)d_out;
  float* wsf = (float*)d_ws;

  float* qss  = wsf;
  float* kss  = wsf + 768;
  float* attn = wsf + 960;
  float* Mt   = wsf + 19392;
  float* bias = wsf + 56256;
  __hip_bfloat16* AF = (__hip_bfloat16*)(wsf + 56544);
  __hip_bfloat16* y    = (__hip_bfloat16*)(wsf + 111872);
  __hip_bfloat16* kbuf = (__hip_bfloat16*)(wsf + 37860608);
  __hip_bfloat16* vbuf = (__hip_bfloat16*)(wsf + 44152064);
  __hip_bfloat16* qfull = (__hip_bfloat16*)d_out;   // scratch: overwritten by k_out

  hipMemsetAsync(wsf, 0, 19392 * sizeof(float), stream);  // qss+kss+attn accumulators
  hipLaunchKernelGGL(k_prep, dim3(1), dim3(256), 0, stream, q_w, kv_w, ln_w, ln_b, AF, bias);
  hipLaunchKernelGGL(k_conv1, dim3(NB * 1024), dim3(256), 0, stream, x, AF, bias, y);
  hipLaunchKernelGGL(k_dwkv, dim3(NB * 96 * 16), dim3(256), 0, stream, y, kv_dw, kbuf, vbuf, kss);
  hipLaunchKernelGGL(k_dwq, dim3(NB * 192 * 16), dim3(256), 0, stream, y, q_dw, qfull, qss);
  hipLaunchKernelGGL(k_qk, dim3(NB * 2 * 64), dim3(256), 0, stream, qfull, kbuf, attn);
  hipLaunchKernelGGL(k_attn_final, dim3(NB), dim3(256), 0, stream, attn, qss, kss, temp, projw, Mt);
  hipLaunchKernelGGL(k_out, dim3(NB * 1024), dim3(256), 0, stream, vbuf, Mt, out);
}

// Round 3
// 664.330 us; speedup vs baseline: 1.3878x; 1.0234x over previous
//
#include <hip/hip_runtime.h>
#include <hip/hip_bf16.h>
#include <stdint.h>

// Problem constants
#define HW    65536          // 256*256
#define NB    4              // batch
#define CIN   192            // dim
#define OYC   288            // 192 q + 96 kv conv1x1 outputs
#define BSTR  200            // B-tile LDS row stride (bf16): 100 words -> 4-bank lane shift
#define EPS   72             // epilogue LDS row stride (bf16), 144 B = 16B-aligned rows

// ---- bf16 helpers (bf16 bits<<16 == fp32 bits) ----
__device__ __forceinline__ float bflo(unsigned u){ return __uint_as_float(u << 16); }
__device__ __forceinline__ float bfhi(unsigned u){ return __uint_as_float(u & 0xffff0000u); }
__device__ __forceinline__ float bf2f(__hip_bfloat16 v){ return __bfloat162float(v); }
__device__ __forceinline__ unsigned short f2bfbits(float f){
  __hip_bfloat16 h = __float2bfloat16(f); return *(unsigned short*)&h;
}

__device__ __forceinline__ void unpack8(uint4 u, float* f) {
  f[0]=bflo(u.x); f[1]=bfhi(u.x); f[2]=bflo(u.y); f[3]=bfhi(u.y);
  f[4]=bflo(u.z); f[5]=bfhi(u.z); f[6]=bflo(u.w); f[7]=bfhi(u.w);
}

union BF8 { uint4 u; __hip_bfloat16 h[8]; };

typedef __attribute__((ext_vector_type(8))) short short8;
typedef __attribute__((ext_vector_type(4))) float floatx4;

// ============================================================================
// K0: fold ln_w into W, emit A in MFMA-fragment order (bf16) + bias.
// Parallelized: blocks 0..31 fill AF, block 32 computes bias.
// ============================================================================
__global__ void k_prep(const float* __restrict__ qw, const float* __restrict__ kvw,
                       const float* __restrict__ lnw, const float* __restrict__ lnb,
                       __hip_bfloat16* __restrict__ AF, float* __restrict__ bias) {
  int blk = blockIdx.x, t = threadIdx.x;
  if (blk < 32) {
    for (int i = blk * 256 + t; i < OYC * CIN; i += 32 * 256) {
      int o = i / CIN, c = i % CIN;
      float w = (o < 192) ? qw[o * 192 + c] : kvw[(o - 192) * 192 + c];
      float val = w * lnw[c];
      int ot = o >> 4, lo = o & 15;
      int ks = c >> 5, cr = c & 31, q = cr >> 3, j = cr & 7;
      int dst = (((ot * 6 + ks) * 64) + q * 16 + lo) * 8 + j;
      AF[dst] = __float2bfloat16(val);
    }
  } else {
    for (int o = t; o < OYC; o += 256) {
      float s = 0.f;
      for (int c = 0; c < CIN; ++c)
        s += ((o < 192) ? qw[o * 192 + c] : kvw[(o - 192) * 192 + c]) * lnb[c];
      bias[o] = s;
    }
  }
}

// ============================================================================
// K1: fused LayerNorm + conv1x1 via bf16 MFMA 16x16x32.
//     New: A-fragment double-buffer prefetch; LDS-transposed vectorized
//     epilogue (two wo-phases reusing Bl as EP[144][EPS]).
// ============================================================================
__global__ __launch_bounds__(256, 4) void k_conv1(const float* __restrict__ x,
                                                  const __hip_bfloat16* __restrict__ AF,
                                                  const float* __restrict__ bias,
                                                  __hip_bfloat16* __restrict__ y) {
  __shared__ __align__(16) __hip_bfloat16 Bl[64 * BSTR];   // reused as EP[144][EPS] in epilogue
  __shared__ float part[4][64][2];
  __shared__ float murs[64][2];
  __shared__ float biasl[OYC];
  int bid = blockIdx.x;
  int b  = bid >> 10;
  int n0 = (bid & 1023) * 64;
  int tid = threadIdx.x;
  int p = tid & 63, g = tid >> 6;

  for (int i = tid; i < OYC; i += 256) biasl[i] = bias[i];

  // phase 1: load 48 channels of pixel p into regs (coalesced), LN stats
  const float* xb = x + (size_t)(b * CIN + g * 48) * HW + n0 + p;
  float xv[48];
  float s = 0.f, ss = 0.f;
#pragma unroll
  for (int j = 0; j < 48; ++j) {
    float v = xb[(size_t)j * HW];
    xv[j] = v; s += v; ss += v * v;
  }
  part[g][p][0] = s; part[g][p][1] = ss;
  __syncthreads();
  if (tid < 64) {
    float s0 = 0.f, s1 = 0.f;
#pragma unroll
    for (int gg = 0; gg < 4; ++gg) { s0 += part[gg][tid][0]; s1 += part[gg][tid][1]; }
    float m = s0 * (1.f / CIN);
    float var = s1 * (1.f / CIN) - m * m;
    murs[tid][0] = m; murs[tid][1] = rsqrtf(var + 1e-5f);
  }
  __syncthreads();
  float mu = murs[p][0], rs = murs[p][1];
#pragma unroll
  for (int j = 0; j < 48; j += 2) {
    unsigned lo = f2bfbits((xv[j]     - mu) * rs);
    unsigned hi = f2bfbits((xv[j + 1] - mu) * rs);
    *(unsigned*)&Bl[p * BSTR + g * 48 + j] = lo | (hi << 16);
  }
  __syncthreads();

  // phase 2: MFMA. wave wo owns o rows [wo*144, +144) = 9 tiles; wn owns px half.
  int wave = tid >> 6, lane = tid & 63;
  int wo = wave >> 1, wn = wave & 1;
  int li = lane & 15, q = lane >> 4;

  floatx4 acc[9][2];
#pragma unroll
  for (int t = 0; t < 9; ++t)
#pragma unroll
    for (int nt = 0; nt < 2; ++nt) acc[t][nt] = (floatx4){0.f, 0.f, 0.f, 0.f};

  // A-fragment double-buffer: frag(t, ks) at abase + (t*6 + ks)*512
  const __hip_bfloat16* abase = AF + ((size_t)(wo * 9) * 6 * 64 + lane) * 8;
  short8 a0[9], a1[9];
#pragma unroll
  for (int t = 0; t < 9; ++t) a0[t] = *(const short8*)(abase + (size_t)(t * 6) * 512);

#pragma unroll
  for (int ks = 0; ks < 6; ++ks) {
    short8 bf0 = *(const short8*)&Bl[(wn * 32 + li) * BSTR + ks * 32 + q * 8];
    short8 bf1 = *(const short8*)&Bl[(wn * 32 + 16 + li) * BSTR + ks * 32 + q * 8];
    if (ks < 5) {
#pragma unroll
      for (int t = 0; t < 9; ++t) {
        short8 v = *(const short8*)(abase + (size_t)(t * 6 + ks + 1) * 512);
        if (ks & 1) a0[t] = v; else a1[t] = v;
      }
    }
#pragma unroll
    for (int t = 0; t < 9; ++t) {
      short8 af = (ks & 1) ? a1[t] : a0[t];
      acc[t][0] = __builtin_amdgcn_mfma_f32_16x16x32_bf16(af, bf0, acc[t][0], 0, 0, 0);
      acc[t][1] = __builtin_amdgcn_mfma_f32_16x16x32_bf16(af, bf1, acc[t][1], 0, 0, 0);
    }
  }

  // epilogue: two phases; wo==ph waves deposit (o-local, px) into EP via LDS,
  // then all threads store rows with 16B/lane. D row = q*4+r, col = li.
  __hip_bfloat16* EP = Bl;
  int row = tid >> 3, cg8 = (tid & 7) * 8;
#pragma unroll
  for (int ph = 0; ph < 2; ++ph) {
    __syncthreads();   // EP region free (Bl reads / previous phase stores done)
    if (wo == ph) {
#pragma unroll
      for (int t = 0; t < 9; ++t)
#pragma unroll
        for (int nt = 0; nt < 2; ++nt)
#pragma unroll
          for (int r = 0; r < 4; ++r) {
            int orow = t * 16 + q * 4 + r;
            int pp = wn * 32 + nt * 16 + li;
            EP[orow * EPS + pp] = __float2bfloat16(acc[t][nt][r] + biasl[ph * 144 + orow]);
          }
    }
    __syncthreads();
#pragma unroll
    for (int it = 0; it < 5; ++it) {
      int rr = it * 32 + row;
      if (rr < 144) {
        uint4 u = *(const uint4*)&EP[rr * EPS + cg8];
        *(uint4*)&y[(size_t)(b * OYC + ph * 144 + rr) * HW + n0 + cg8] = u;
      }
    }
  }
}

// ============================================================================
// K2: depthwise 3x3 over kv channels. Block = (b, ch, 16-row tile). (unchanged)
// ============================================================================
__global__ __launch_bounds__(256) void k_dwkv(const __hip_bfloat16* __restrict__ y,
                                              const float* __restrict__ kvdw,
                                              __hip_bfloat16* __restrict__ kbuf,
                                              __hip_bfloat16* __restrict__ vbuf,
                                              float* __restrict__ kss) {
  __shared__ __align__(16) __hip_bfloat16 stage[18 * 256];
  int bid = blockIdx.x;
  int hb = bid & 15;                  // 16 row-tiles
  int ck = (bid >> 4) % 96;
  int b  = bid / (16 * 96);
  int tid = threadIdx.x;
  int h0 = hb * 16;

  const __hip_bfloat16* yp = y + (size_t)(b * OYC + 192 + ck) * HW;
  for (int i = tid; i < 18 * 32; i += 256) {
    int ry = i >> 5, seg = i & 31;
    int hh = h0 - 1 + ry;
    uint4 u = make_uint4(0u, 0u, 0u, 0u);
    if ((unsigned)hh < 256u) u = *(const uint4*)(yp + hh * 256 + seg * 8);
    *(uint4*)&stage[ry * 256 + seg * 8] = u;
  }
  __syncthreads();

  float w[9];
#pragma unroll
  for (int i = 0; i < 9; ++i) w[i] = kvdw[ck * 9 + i];

  int cg = tid & 31, rg = tid >> 5;   // 8 rowpairs x 32 colgroups
  int c0 = cg * 8;
  bool isk = (ck < 48);
  __hip_bfloat16* ob = (isk ? kbuf : vbuf) + (size_t)(b * 48 + (ck % 48)) * HW;
  float ssq = 0.f;
#pragma unroll
  for (int rr = 0; rr < 2; ++rr) {
    int orow = rg * 2 + rr;
    float o[8];
#pragma unroll
    for (int j = 0; j < 8; ++j) o[j] = 0.f;
#pragma unroll
    for (int ry = 0; ry < 3; ++ry) {
      const __hip_bfloat16* rb = &stage[(orow + ry) * 256];
      float v[8];
      unpack8(*(const uint4*)&rb[c0], v);
      float vl = (c0 > 0)       ? bf2f(rb[c0 - 1]) : 0.f;
      float vr = (c0 + 8 < 256) ? bf2f(rb[c0 + 8]) : 0.f;
      float wl = w[ry * 3], wm = w[ry * 3 + 1], wr = w[ry * 3 + 2];
      o[0] = fmaf(wl, vl, fmaf(wm, v[0], fmaf(wr, v[1], o[0])));
#pragma unroll
      for (int j = 1; j < 7; ++j)
        o[j] = fmaf(wl, v[j-1], fmaf(wm, v[j], fmaf(wr, v[j+1], o[j])));
      o[7] = fmaf(wl, v[6], fmaf(wm, v[7], fmaf(wr, vr, o[7])));
    }
    BF8 t;
#pragma unroll
    for (int j = 0; j < 8; ++j) {
      t.h[j] = __float2bfloat16(o[j]);
      if (isk) { float fv = bf2f(t.h[j]); ssq += fv * fv; }
    }
    *(uint4*)(ob + (size_t)(h0 + orow) * 256 + c0) = t.u;
  }
  if (isk) {
#pragma unroll
    for (int off = 32; off > 0; off >>= 1) ssq += __shfl_down(ssq, off);
    __shared__ float ws4[4];
    if ((tid & 63) == 0) ws4[tid >> 6] = ssq;
    __syncthreads();
    if (tid == 0) atomicAdd(&kss[b * 48 + ck], ws4[0] + ws4[1] + ws4[2] + ws4[3]);
  }
}

// ============================================================================
// K3a: depthwise 3x3 over the 192 q channels -> qfull (scratch in d_out),
//      fused sum(q^2). (unchanged)
// ============================================================================
__global__ __launch_bounds__(256) void k_dwq(const __hip_bfloat16* __restrict__ y,
                                             const float* __restrict__ qdw,
                                             __hip_bfloat16* __restrict__ qfull,
                                             float* __restrict__ qss) {
  __shared__ __align__(16) __hip_bfloat16 stage[18 * 256];
  int bid = blockIdx.x;
  int hb = bid & 15;                  // 16 row-tiles
  int c  = (bid >> 4) % 192;
  int b  = bid / (16 * 192);
  int tid = threadIdx.x;
  int h0 = hb * 16;

  const __hip_bfloat16* yp = y + (size_t)(b * OYC + c) * HW;
  for (int i = tid; i < 18 * 32; i += 256) {
    int ry = i >> 5, seg = i & 31;
    int hh = h0 - 1 + ry;
    uint4 u = make_uint4(0u, 0u, 0u, 0u);
    if ((unsigned)hh < 256u) u = *(const uint4*)(yp + hh * 256 + seg * 8);
    *(uint4*)&stage[ry * 256 + seg * 8] = u;
  }
  __syncthreads();

  float w[9];
#pragma unroll
  for (int i = 0; i < 9; ++i) w[i] = qdw[c * 9 + i];

  int cg = tid & 31, rg = tid >> 5;   // 8 rowpairs x 32 colgroups
  int c0 = cg * 8;
  __hip_bfloat16* ob = qfull + (size_t)(b * CIN + c) * HW;
  float ssq = 0.f;
#pragma unroll
  for (int rr = 0; rr < 2; ++rr) {
    int orow = rg * 2 + rr;
    float o[8];
#pragma unroll
    for (int j = 0; j < 8; ++j) o[j] = 0.f;
#pragma unroll
    for (int ry = 0; ry < 3; ++ry) {
      const __hip_bfloat16* rb = &stage[(orow + ry) * 256];
      float v[8];
      unpack8(*(const uint4*)&rb[c0], v);
      float vl = (c0 > 0)       ? bf2f(rb[c0 - 1]) : 0.f;
      float vr = (c0 + 8 < 256) ? bf2f(rb[c0 + 8]) : 0.f;
      float wl = w[ry * 3], wm = w[ry * 3 + 1], wr = w[ry * 3 + 2];
      o[0] = fmaf(wl, vl, fmaf(wm, v[0], fmaf(wr, v[1], o[0])));
#pragma unroll
      for (int j = 1; j < 7; ++j)
        o[j] = fmaf(wl, v[j-1], fmaf(wm, v[j], fmaf(wr, v[j+1], o[j])));
      o[7] = fmaf(wl, v[6], fmaf(wm, v[7], fmaf(wr, vr, o[7])));
    }
    BF8 t;
#pragma unroll
    for (int j = 0; j < 8; ++j) {
      t.h[j] = __float2bfloat16(o[j]);
      float fv = bf2f(t.h[j]); ssq += fv * fv;
    }
    *(uint4*)(ob + (size_t)(h0 + orow) * 256 + c0) = t.u;
  }
#pragma unroll
  for (int off = 32; off > 0; off >>= 1) ssq += __shfl_down(ssq, off);
  __shared__ float ws4[4];
  if ((tid & 63) == 0) ws4[tid >> 6] = ssq;
  __syncthreads();
  if (tid == 0) atomicAdd(&qss[b * 192 + c], ws4[0] + ws4[1] + ws4[2] + ws4[3]);
}

// ============================================================================
// K3b: QK^T via bf16 MFMA. (unchanged)
// ============================================================================
__global__ __launch_bounds__(256) void k_qk(const __hip_bfloat16* __restrict__ qfull,
                                            const __hip_bfloat16* __restrict__ kbuf,
                                            float* __restrict__ attn) {
  __shared__ float red[96 * 33];
  int bid = blockIdx.x;
  int ck  = bid & 63;
  int kvh = (bid >> 6) & 1;
  int b   = bid >> 7;
  int tid = threadIdx.x;
  int wave = tid >> 6, lane = tid & 63;
  int li = lane & 15, qd = lane >> 4;

  for (int i = tid; i < 96 * 33; i += 256) red[i] = 0.f;

  const __hip_bfloat16* qp = qfull + (size_t)(b * CIN + kvh * 96) * HW;
  const __hip_bfloat16* kp = kbuf  + (size_t)(b * 48 + kvh * 24) * HW;
  int n0 = ck * 1024 + wave * 256;

  floatx4 acc[6][2];
#pragma unroll
  for (int mt = 0; mt < 6; ++mt) {
    acc[mt][0] = (floatx4){0.f, 0.f, 0.f, 0.f};
    acc[mt][1] = (floatx4){0.f, 0.f, 0.f, 0.f};
  }

  int kr1 = 16 + li; if (kr1 > 23) kr1 = 23;   // clamp pad rows of N-tile 1
  for (int ks = 0; ks < 8; ++ks) {
    int nn = n0 + ks * 32 + qd * 8;
    short8 bk0 = *(const short8*)(kp + (size_t)li  * HW + nn);
    short8 bk1 = *(const short8*)(kp + (size_t)kr1 * HW + nn);
#pragma unroll
    for (int mt = 0; mt < 6; ++mt) {
      short8 aq = *(const short8*)(qp + (size_t)(mt * 16 + li) * HW + nn);
      acc[mt][0] = __builtin_amdgcn_mfma_f32_16x16x32_bf16(aq, bk0, acc[mt][0], 0, 0, 0);
      acc[mt][1] = __builtin_amdgcn_mfma_f32_16x16x32_bf16(aq, bk1, acc[mt][1], 0, 0, 0);
    }
  }
  __syncthreads();   // red[] zero complete

  // D layout: col = lane&15 (n = k-ch), row = (lane>>4)*4 + r (m within tile)
#pragma unroll
  for (int mt = 0; mt < 6; ++mt) {
#pragma unroll
    for (int nt = 0; nt < 2; ++nt) {
      int n = nt * 16 + li;
      if (n < 24) {
#pragma unroll
        for (int r = 0; r < 4; ++r) {
          int m = mt * 16 + qd * 4 + r;
          atomicAdd(&red[m * 33 + n], acc[mt][nt][r]);
        }
      }
    }
  }
  __syncthreads();

  for (int i = tid; i < 96 * 24; i += 256) {
    int m = i / 24, d = i % 24;
    int head = kvh * 4 + m / 24, cp = m % 24;
    atomicAdd(&attn[(((b * 8 + head) * 24) + cp) * 24 + d], red[m * 33 + d]);
  }
}

// ============================================================================
// K4: l2norm scaling + temperature + softmax, fold proj_w. (unchanged)
// ============================================================================
__global__ void k_attn_final(const float* __restrict__ attn, const float* __restrict__ qss,
                             const float* __restrict__ kss, const float* __restrict__ temp,
                             const float* __restrict__ projw, float* __restrict__ Mt) {
  int b = blockIdx.x;
  int t = threadIdx.x;
  __shared__ float as_[96 * 25];
  float acc[48];
#pragma unroll
  for (int j = 0; j < 48; ++j) acc[j] = 0.f;
  for (int kvh = 0; kvh < 2; ++kvh) {
    __syncthreads();
    if (t < 96) {
      int row = kvh * 96 + t;           // global q channel
      int h = row / 24, cp = row % 24;
      float rq = 1.f / fmaxf(sqrtf(qss[b * 192 + row]), 1e-12f);
      float tp = temp[h];
      float lg[24]; float mx = -1e30f;
#pragma unroll
      for (int d = 0; d < 24; ++d) {
        float rk = 1.f / fmaxf(sqrtf(kss[b * 48 + kvh * 24 + d]), 1e-12f);
        float l = attn[(((b * 8 + h) * 24) + cp) * 24 + d] * rq * rk * tp;
        lg[d] = l; mx = fmaxf(mx, l);
      }
      float s = 0.f;
#pragma unroll
      for (int d = 0; d < 24; ++d) { lg[d] = __expf(lg[d] - mx); s += lg[d]; }
      float inv = 1.f / s;
#pragma unroll
      for (int d = 0; d < 24; ++d) as_[t * 25 + d] = lg[d] * inv;
    }
    __syncthreads();
    if (t < 192) {
      for (int cc = 0; cc < 96; ++cc) {
        float pw = projw[t * 192 + kvh * 96 + cc];
        const float* ar = &as_[cc * 25];
#pragma unroll
        for (int d = 0; d < 24; ++d) acc[kvh * 24 + d] = fmaf(pw, ar[d], acc[kvh * 24 + d]);
      }
    }
  }
  if (t < 192) {
#pragma unroll
    for (int j = 0; j < 48; ++j) Mt[((size_t)b * 48 + j) * 192 + t] = acc[j];
  }
}

// ============================================================================
// K5: out[b][o][n] = sum_j Mt[b][j][o] * v[b][j][n]   (fp32 output)
//     New: 256-px blocks, 4 px/thread, float4 Mt loads, float4 stores.
// ============================================================================
__global__ __launch_bounds__(256) void k_out(const __hip_bfloat16* __restrict__ vbuf,
                                             const float* __restrict__ Mt,
                                             float* __restrict__ out) {
  __shared__ __align__(16) __hip_bfloat16 lv[48 * 256];
  int bid = blockIdx.x;
  int b  = bid >> 8;
  int n0 = (bid & 255) * 256;
  int tid = threadIdx.x;
  const __hip_bfloat16* vb = vbuf + (size_t)b * 48 * HW + n0;
  for (int i = tid; i < 48 * 32; i += 256) {
    int c = i >> 5, seg = i & 31;
    *(uint4*)&lv[c * 256 + seg * 8] = *(const uint4*)(vb + (size_t)c * HW + seg * 8);
  }
  __syncthreads();
  int wave = tid >> 6, ln = tid & 63;
  const float* mb = Mt + (size_t)b * 48 * 192;
  for (int ch = 0; ch < 2; ++ch) {
    int o0 = wave * 48 + ch * 24;
    float acc[24][4];
#pragma unroll
    for (int j = 0; j < 24; ++j)
#pragma unroll
      for (int e = 0; e < 4; ++e) acc[j][e] = 0.f;
    for (int c = 0; c < 48; ++c) {
      float xv[4];
      uint2 u = *(const uint2*)&lv[c * 256 + ln * 4];
      xv[0] = bflo(u.x); xv[1] = bfhi(u.x); xv[2] = bflo(u.y); xv[3] = bfhi(u.y);
      const float* mrow = mb + c * 192 + o0;
      float4 m[6];
#pragma unroll
      for (int gg = 0; gg < 6; ++gg) m[gg] = *(const float4*)(mrow + gg * 4);
      const float* mf = (const float*)&m[0];
#pragma unroll
      for (int j = 0; j < 24; ++j) {
        float mv = mf[j];
#pragma unroll
        for (int e = 0; e < 4; ++e) acc[j][e] = fmaf(mv, xv[e], acc[j][e]);
      }
    }
#pragma unroll
    for (int j = 0; j < 24; ++j) {
      float4 st = make_float4(acc[j][0], acc[j][1], acc[j][2], acc[j][3]);
      *(float4*)&out[(size_t)(b * 192 + o0 + j) * HW + n0 + ln * 4] = st;
    }
  }
}

// ============================================================================
// ws layout (float offsets):
//  0        qss   [4*192]      = 768
//  768      kss   [4*48]       = 192
//  960      attn  [4*8*24*24]  = 18432
//  19392    Mt    [4*48*192]   = 36864
//  56256    bias  [288]
//  56544    AF  bf16 [288*192] (= 27648 float slots)
//  111872   y   bf16 [4*288*HW]
//  37860608 kbuf bf16 [4*48*HW]
//  44152064 vbuf bf16 [4*48*HW]
// qfull (bf16 [4*192*HW] = 100.7 MB) lives in d_out scratch (201 MB fp32),
// dead before k_out overwrites it.
// ============================================================================
extern "C" void kernel_launch(void* const* d_in, const int* in_sizes, int n_in,
                              void* d_out, int out_size, void* d_ws, size_t ws_size,
                              hipStream_t stream) {
  const float* x     = (const float*)d_in[0];
  const float* ln_w  = (const float*)d_in[1];
  const float* ln_b  = (const float*)d_in[2];
  const float* q_w   = (const float*)d_in[3];
  const float* q_dw  = (const float*)d_in[4];
  const float* kv_w  = (const float*)d_in[5];
  const float* kv_dw = (const float*)d_in[6];
  const float* projw = (const float*)d_in[7];
  const float* temp  = (const float*)d_in[8];
  float* out = (float*)d_out;
  float* wsf = (float*)d_ws;

  float* qss  = wsf;
  float* kss  = wsf + 768;
  float* attn = wsf + 960;
  float* Mt   = wsf + 19392;
  float* bias = wsf + 56256;
  __hip_bfloat16* AF = (__hip_bfloat16*)(wsf + 56544);
  __hip_bfloat16* y    = (__hip_bfloat16*)(wsf + 111872);
  __hip_bfloat16* kbuf = (__hip_bfloat16*)(wsf + 37860608);
  __hip_bfloat16* vbuf = (__hip_bfloat16*)(wsf + 44152064);
  __hip_bfloat16* qfull = (__hip_bfloat16*)d_out;   // scratch: overwritten by k_out

  hipMemsetAsync(wsf, 0, 19392 * sizeof(float), stream);  // qss+kss+attn accumulators
  hipLaunchKernelGGL(k_prep, dim3(33), dim3(256), 0, stream, q_w, kv_w, ln_w, ln_b, AF, bias);
  hipLaunchKernelGGL(k_conv1, dim3(NB * 1024), dim3(256), 0, stream, x, AF, bias, y);
  hipLaunchKernelGGL(k_dwkv, dim3(NB * 96 * 16), dim3(256), 0, stream, y, kv_dw, kbuf, vbuf, kss);
  hipLaunchKernelGGL(k_dwq, dim3(NB * 192 * 16), dim3(256), 0, stream, y, q_dw, qfull, qss);
  hipLaunchKernelGGL(k_qk, dim3(NB * 2 * 64), dim3(256), 0, stream, qfull, kbuf, attn);
  hipLaunchKernelGGL(k_attn_final, dim3(NB), dim3(256), 0, stream, attn, qss, kss, temp, projw, Mt);
  hipLaunchKernelGGL(k_out, dim3(NB * 256), dim3(256), 0, stream, vbuf, Mt, out);
}